// Round 6
// baseline (355.501 us; speedup 1.0000x reference)
//
#include <hip/hip_runtime.h>
#include <hip/hip_bf16.h>

typedef __bf16 bf16x8 __attribute__((ext_vector_type(8)));
typedef float  f32x4  __attribute__((ext_vector_type(4)));

#define MFMA(a, b, c) __builtin_amdgcn_mfma_f32_16x16x32_bf16((a), (b), (c), 0, 0, 0)

static constexpr float SC_L2E = 0.03125f * 1.44269504088896341f;  // (1/sqrt(1024)) * log2(e)
static constexpr float INV_NQ = 1.0f / 4096.0f;                   // mean over 4S rows

__device__ inline bf16x8 ld_cvt_bf8(const float* __restrict__ p) {
    f32x4 x0 = *(const f32x4*)p;
    f32x4 x1 = *(const f32x4*)(p + 4);
    bf16x8 r;
    r[0] = (__bf16)x0[0]; r[1] = (__bf16)x0[1]; r[2] = (__bf16)x0[2]; r[3] = (__bf16)x0[3];
    r[4] = (__bf16)x1[0]; r[5] = (__bf16)x1[1]; r[6] = (__bf16)x1[2]; r[7] = (__bf16)x1[3];
    return r;
}

// ---- Kernel T: transpose 4 projection weights [1024,128] -> bf16 [128,1024] ----
// 64x64 LDS tile; coalesced read AND write. grid 128 = 4 mat x 16 rtile x 2 ctile.
__global__ __launch_bounds__(256) void kT(const float* __restrict__ Dq, const float* __restrict__ Vq,
                                          const float* __restrict__ Dk, const float* __restrict__ Vk,
                                          __bf16* __restrict__ Wt) {
    __shared__ float tile[64][65];
    int bx = blockIdx.x;
    int m = bx >> 5, rt = (bx >> 1) & 15, ct = bx & 1;
    const float* W = (m == 0) ? Dq : (m == 1) ? Vq : (m == 2) ? Dk : Vk;
    int t = threadIdx.x;
    int tr = t >> 6, tc = t & 63;
#pragma unroll
    for (int i = 0; i < 16; i++) {
        int rl = tr + i * 4;
        tile[rl][tc] = W[(size_t)(rt * 64 + rl) * 128 + ct * 64 + tc];
    }
    __syncthreads();
#pragma unroll
    for (int i = 0; i < 16; i++) {
        int cl = tr + i * 4;
        Wt[(size_t)m * 131072 + (size_t)(ct * 64 + cl) * 1024 + rt * 64 + tc] = (__bf16)tile[tc][cl];
    }
}

// ---- Kernel P: fused q+k projections -> bf16 Q[b][4096][128], K[b][4096][128] ----
// grid 1024 x 16 rows; 4 waves/block; wave w owns col-frags {2w,2w+1} of BOTH Q and K.
// 4 accum frags/wave -> low VGPR -> 4 blocks/CU resident = 16 waves/CU.
__global__ __launch_bounds__(256) void kProj(
    const float* __restrict__ drums, const float* __restrict__ vocals,
    const float* __restrict__ bass,  const float* __restrict__ other,
    const float* __restrict__ Dqb, const float* __restrict__ Vqb,
    const float* __restrict__ Dkb, const float* __restrict__ Vkb,
    const __bf16* __restrict__ Wt, __bf16* __restrict__ Qb, __bf16* __restrict__ Kb) {
    int grow0 = blockIdx.x * 16;
    int b    = grow0 >> 12;
    int r4   = grow0 & 4095;
    int stem = r4 >> 10;
    int rin  = r4 & 1023;

    const float* X = (stem == 0) ? drums : (stem == 1) ? vocals : (stem == 2) ? bass : other;
    const __bf16* WQ = Wt + (size_t)((stem == 0) ? 0 : 1) * 131072;
    const __bf16* WK = Wt + (size_t)((stem == 0) ? 2 : 3) * 131072;
    const float* bQ = (stem == 0) ? Dqb : Vqb;
    const float* bK = (stem == 0) ? Dkb : Vkb;

    int lane = threadIdx.x & 63, wid = threadIdx.x >> 6;
    int l16 = lane & 15, g = lane >> 4;

    f32x4 aQ[2], aK[2];
#pragma unroll
    for (int j = 0; j < 2; j++) { aQ[j] = (f32x4){0.f,0.f,0.f,0.f}; aK[j] = (f32x4){0.f,0.f,0.f,0.f}; }

    const float*  xr  = X  + ((size_t)b * 1024 + rin + l16) * 1024;
    const __bf16* wq0 = WQ + (size_t)(wid * 32 + l16) * 1024;
    const __bf16* wq1 = wq0 + 16 * 1024;
    const __bf16* wk0 = WK + (size_t)(wid * 32 + l16) * 1024;
    const __bf16* wk1 = wk0 + 16 * 1024;

    for (int k0 = 0; k0 < 1024; k0 += 32) {
        int ko = k0 + g * 8;
        bf16x8 a = ld_cvt_bf8(xr + ko);
        aQ[0] = MFMA(a, *(const bf16x8*)(wq0 + ko), aQ[0]);
        aQ[1] = MFMA(a, *(const bf16x8*)(wq1 + ko), aQ[1]);
        aK[0] = MFMA(a, *(const bf16x8*)(wk0 + ko), aK[0]);
        aK[1] = MFMA(a, *(const bf16x8*)(wk1 + ko), aK[1]);
    }
    size_t obase = (size_t)b * 4096 + (size_t)stem * 1024 + rin;
#pragma unroll
    for (int cf = 0; cf < 2; cf++) {
        int col = (wid * 2 + cf) * 16 + l16;
        float bvq = bQ[col], bvk = bK[col];
#pragma unroll
        for (int r = 0; r < 4; r++) {
            int row = g * 4 + r;
            Qb[(obase + row) * 128 + col] = (__bf16)(aQ[cf][r] + bvq);
            Kb[(obase + row) * 128 + col] = (__bf16)(aK[cf][r] + bvk);
        }
    }
}

// ---- Kernel S1: row sums l[q] = sum_k exp(s_qk) ----
// grid 1024: [b(4)][rowtile(32)][colchunk(8)]; block 4 waves, wave 32 rows x 512-col stream.
// K tile (64 cols x 128) LDS-staged per block, XOR-swizzled ((row&7)<<4).
__global__ __launch_bounds__(256) void kRowSum(const __bf16* __restrict__ Qb,
                                               const __bf16* __restrict__ Kb,
                                               float* __restrict__ lsum) {
    __shared__ uint4 ktile[1024];    // 64 rows x 128 bf16 = 16 KB
    int bx = blockIdx.x;
    int cc = bx & 7, tile = (bx >> 3) & 31, b = bx >> 8;
    int lane = threadIdx.x & 63, wid = threadIdx.x >> 6;
    int l16 = lane & 15, g = lane >> 4;
    int R  = tile * 128 + wid * 32;
    int C0 = cc * 512;
    const __bf16* Qr = Qb + (size_t)b * 4096 * 128;
    const __bf16* Kr = Kb + (size_t)b * 4096 * 128;

    bf16x8 a[2][4];
#pragma unroll
    for (int rf = 0; rf < 2; rf++)
#pragma unroll
        for (int kf = 0; kf < 4; kf++)
            a[rf][kf] = *(const bf16x8*)(Qr + (size_t)(R + rf * 16 + l16) * 128 + kf * 32 + g * 8);

    int sr = threadIdx.x >> 2, sseg = threadIdx.x & 3;   // stage: row, 64B-segment
    char* kbc = (char*)ktile;
    int swm = (sr & 7) << 4;

    uint4 st[4];
    {
        const char* src = (const char*)(Kr + (size_t)(C0 + sr) * 128) + sseg * 64;
#pragma unroll
        for (int j = 0; j < 4; j++) st[j] = *(const uint4*)(src + j * 16);
    }

    float rs[2][4] = {};
    for (int s = 0; s < 8; ++s) {
        __syncthreads();
#pragma unroll
        for (int j = 0; j < 4; j++)
            *(uint4*)(kbc + sr * 256 + ((sseg * 64 + j * 16) ^ swm)) = st[j];
        __syncthreads();
        if (s < 7) {
            const char* src = (const char*)(Kr + (size_t)(C0 + (s + 1) * 64 + sr) * 128) + sseg * 64;
#pragma unroll
            for (int j = 0; j < 4; j++) st[j] = *(const uint4*)(src + j * 16);
        }
#pragma unroll
        for (int ctl = 0; ctl < 4; ++ctl) {
            int r2 = ctl * 16 + l16;
            int rm = (r2 & 7) << 4;
            f32x4 acc0 = (f32x4){0.f,0.f,0.f,0.f};
            f32x4 acc1 = (f32x4){0.f,0.f,0.f,0.f};
#pragma unroll
            for (int kf = 0; kf < 4; kf++) {
                bf16x8 bv = *(const bf16x8*)(kbc + r2 * 256 + ((kf * 64 + g * 16) ^ rm));
                acc0 = MFMA(a[0][kf], bv, acc0);
                acc1 = MFMA(a[1][kf], bv, acc1);
            }
#pragma unroll
            for (int r = 0; r < 4; r++) {
                rs[0][r] += exp2f(acc0[r] * SC_L2E);
                rs[1][r] += exp2f(acc1[r] * SC_L2E);
            }
        }
    }
#pragma unroll
    for (int rf = 0; rf < 2; rf++)
#pragma unroll
        for (int r = 0; r < 4; r++) {
            float v = rs[rf][r];
#pragma unroll
            for (int m = 1; m < 16; m <<= 1) v += __shfl_xor(v, m);
            if (l16 == 0) atomicAdd(&lsum[(size_t)b * 4096 + R + rf * 16 + g * 4 + r], v);
        }
}

// ---- Kernel I: linv = 1/lsum, 16384 elems ----
__global__ __launch_bounds__(256) void kInv(const float* __restrict__ lsum, float* __restrict__ linv) {
    int i = (blockIdx.x * 256 + threadIdx.x) * 4;
    f32x4 v = *(const f32x4*)(lsum + i);
    f32x4 r = (f32x4){1.f / v[0], 1.f / v[1], 1.f / v[2], 1.f / v[3]};
    *(f32x4*)(linv + i) = r;
}

// ---- Kernel S2: col sums w[k] = sum_q exp(s_qk)/l_q ----
// grid 1024: [b(4)][coltile(32)][rowchunk(8)]; wave 32 cols x 512-row stream; Q LDS-staged.
__global__ __launch_bounds__(256) void kColSum(const __bf16* __restrict__ Qb,
                                               const __bf16* __restrict__ Kb,
                                               const float* __restrict__ linv,
                                               float* __restrict__ wsum) {
    __shared__ uint4 qtile[1024];    // 64 rows x 128 bf16 = 16 KB
    __shared__ float li[512];
    int bx = blockIdx.x;
    int rc = bx & 7, tile = (bx >> 3) & 31, b = bx >> 8;
    int lane = threadIdx.x & 63, wid = threadIdx.x >> 6;
    int l16 = lane & 15, g = lane >> 4;
    int C  = tile * 128 + wid * 32;
    int R0 = rc * 512;
    const __bf16* Qr = Qb + (size_t)b * 4096 * 128;
    const __bf16* Kr = Kb + (size_t)b * 4096 * 128;

    if (threadIdx.x < 128)
        *(f32x4*)(li + threadIdx.x * 4) = *(const f32x4*)(linv + (size_t)b * 4096 + R0 + threadIdx.x * 4);

    bf16x8 kb[2][4];
#pragma unroll
    for (int cf = 0; cf < 2; cf++)
#pragma unroll
        for (int kf = 0; kf < 4; kf++)
            kb[cf][kf] = *(const bf16x8*)(Kr + (size_t)(C + cf * 16 + l16) * 128 + kf * 32 + g * 8);

    int sr = threadIdx.x >> 2, sseg = threadIdx.x & 3;
    char* qbc = (char*)qtile;
    int swm = (sr & 7) << 4;

    uint4 st[4];
    {
        const char* src = (const char*)(Qr + (size_t)(R0 + sr) * 128) + sseg * 64;
#pragma unroll
        for (int j = 0; j < 4; j++) st[j] = *(const uint4*)(src + j * 16);
    }

    float cs[2] = {0.f, 0.f};
    for (int s = 0; s < 8; ++s) {
        __syncthreads();
#pragma unroll
        for (int j = 0; j < 4; j++)
            *(uint4*)(qbc + sr * 256 + ((sseg * 64 + j * 16) ^ swm)) = st[j];
        __syncthreads();
        if (s < 7) {
            const char* src = (const char*)(Qr + (size_t)(R0 + (s + 1) * 64 + sr) * 128) + sseg * 64;
#pragma unroll
            for (int j = 0; j < 4; j++) st[j] = *(const uint4*)(src + j * 16);
        }
#pragma unroll
        for (int ctl = 0; ctl < 4; ++ctl) {
            int r2 = ctl * 16 + l16;
            int rm = (r2 & 7) << 4;
            f32x4 acc0 = (f32x4){0.f,0.f,0.f,0.f};
            f32x4 acc1 = (f32x4){0.f,0.f,0.f,0.f};
#pragma unroll
            for (int kf = 0; kf < 4; kf++) {
                bf16x8 av = *(const bf16x8*)(qbc + r2 * 256 + ((kf * 64 + g * 16) ^ rm));
                acc0 = MFMA(av, kb[0][kf], acc0);
                acc1 = MFMA(av, kb[1][kf], acc1);
            }
            int ib = s * 64 + ctl * 16 + g * 4;
#pragma unroll
            for (int r = 0; r < 4; r++) {
                float lv = li[ib + r];
                cs[0] += exp2f(acc0[r] * SC_L2E) * lv;
                cs[1] += exp2f(acc1[r] * SC_L2E) * lv;
            }
        }
    }
#pragma unroll
    for (int cf = 0; cf < 2; cf++) {
        float v = cs[cf];
        v += __shfl_xor(v, 16);
        v += __shfl_xor(v, 32);
        if (lane < 16) atomicAdd(&wsum[(size_t)b * 4096 + C + cf * 16 + lane], v);
    }
}

// ---- Kernel Y: weighted stem sums (fp32) ----
// grid 1024: [b(4)][stem(4)][kchunk(64)] x 16 rows; y[b][seg][1024], alpha[b][seg]
__global__ __launch_bounds__(256) void kY(
    const float* __restrict__ drums, const float* __restrict__ vocals,
    const float* __restrict__ bass,  const float* __restrict__ other,
    const float* __restrict__ wsum, float* __restrict__ y, float* __restrict__ alpha) {
    __shared__ float ws[16];
    int bx = blockIdx.x;
    int b = bx >> 8, stem = (bx >> 6) & 3, kc = bx & 63;
    const float* X = (stem == 0) ? drums : (stem == 1) ? vocals : (stem == 2) ? bass : other;
    int t = threadIdx.x;
    float wv = 0.f;
    if (t < 16) { wv = wsum[(size_t)b * 4096 + stem * 1024 + kc * 16 + t] * INV_NQ; ws[t] = wv; }
    __syncthreads();

    f32x4 acc = (f32x4){0.f, 0.f, 0.f, 0.f};
    const float* xp = X + ((size_t)b * 1024 + kc * 16) * 1024 + t * 4;
#pragma unroll 4
    for (int i = 0; i < 16; i++) {
        f32x4 xv = *(const f32x4*)(xp + (size_t)i * 1024);
        float wvi = ws[i];
        acc[0] += wvi * xv[0]; acc[1] += wvi * xv[1]; acc[2] += wvi * xv[2]; acc[3] += wvi * xv[3];
    }
    int seg = (stem == 0) ? 0 : 1;
    float* yp = y + ((size_t)b * 2 + seg) * 1024 + t * 4;
    atomicAdd(yp + 0, acc[0]); atomicAdd(yp + 1, acc[1]);
    atomicAdd(yp + 2, acc[2]); atomicAdd(yp + 3, acc[3]);

    if (t < 16) {
        float s = wv;
        s += __shfl_xor(s, 1); s += __shfl_xor(s, 2);
        s += __shfl_xor(s, 4); s += __shfl_xor(s, 8);
        if (t == 0) atomicAdd(alpha + b * 2 + seg, s);
    }
}

// ---- Kernel F: out[b][d] = yD@DvW + yV@VvW + aD*Dvb + aV*Vvb ----
// grid 512: [b(4)][dstripe(4)][kchunk(32)]
__global__ __launch_bounds__(256) void kFinal(
    const float* __restrict__ DvW, const float* __restrict__ Dvb,
    const float* __restrict__ VvW, const float* __restrict__ Vvb,
    const float* __restrict__ y, const float* __restrict__ alpha,
    float* __restrict__ out) {
    __shared__ float yD[32], yV[32];
    int bx = blockIdx.x;
    int b = bx >> 7, dstripe = (bx >> 5) & 3, kc = bx & 31;
    int t = threadIdx.x;
    if (t < 32) {
        yD[t] = y[((size_t)b * 2 + 0) * 1024 + kc * 32 + t];
        yV[t] = y[((size_t)b * 2 + 1) * 1024 + kc * 32 + t];
    }
    __syncthreads();

    int d = dstripe * 256 + t;
    const float* pD = DvW + (size_t)(kc * 32) * 1024 + d;
    const float* pV = VvW + (size_t)(kc * 32) * 1024 + d;
    float acc = 0.f;
#pragma unroll 4
    for (int k = 0; k < 32; k++)
        acc += yD[k] * pD[(size_t)k * 1024] + yV[k] * pV[(size_t)k * 1024];
    if (kc == 0) acc += alpha[b * 2] * Dvb[d] + alpha[b * 2 + 1] * Vvb[d];
    atomicAdd(out + (size_t)b * 1024 + d, acc);
}

extern "C" void kernel_launch(void* const* d_in, const int* in_sizes, int n_in,
                              void* d_out, int out_size, void* d_ws, size_t ws_size,
                              hipStream_t stream) {
    const float* drums  = (const float*)d_in[0];
    const float* vocals = (const float*)d_in[1];
    const float* bass   = (const float*)d_in[2];
    const float* other  = (const float*)d_in[3];
    const float* DqW = (const float*)d_in[4];
    const float* Dqb = (const float*)d_in[5];
    const float* DkW = (const float*)d_in[6];
    const float* Dkb = (const float*)d_in[7];
    const float* DvW = (const float*)d_in[8];
    const float* Dvb = (const float*)d_in[9];
    const float* VqW = (const float*)d_in[10];
    const float* Vqb = (const float*)d_in[11];
    const float* VkW = (const float*)d_in[12];
    const float* Vkb = (const float*)d_in[13];
    const float* VvW = (const float*)d_in[14];
    const float* Vvb = (const float*)d_in[15];
    float* out = (float*)d_out;

    char* ws = (char*)d_ws;
    __bf16* Qb   = (__bf16*)(ws);                                  // 4 MB
    __bf16* Kb   = (__bf16*)(ws + (4u << 20));                     // 4 MB
    __bf16* Wt   = (__bf16*)(ws + (8u << 20));                     // 1 MB
    float*  lsum = (float*)(ws + (9u << 20));                      // 64 KB
    float*  wsum = (float*)(ws + (9u << 20) + (64u << 10));        // 64 KB
    float*  y    = (float*)(ws + (9u << 20) + (128u << 10));       // 32 KB
    float*  alph = (float*)(ws + (9u << 20) + (160u << 10));       // 32 B
    float*  linv = (float*)(ws + (9u << 20) + (192u << 10));       // 64 KB

    // zero lsum/wsum/y/alpha (contiguous) and out (accumulated via atomics)
    hipMemsetAsync(lsum, 0, (160u << 10) + 32, stream);
    hipMemsetAsync(out, 0, (size_t)out_size * sizeof(float), stream);

    kT<<<128, 256, 0, stream>>>(DqW, VqW, DkW, VkW, Wt);
    kProj<<<1024, 256, 0, stream>>>(drums, vocals, bass, other, Dqb, Vqb, Dkb, Vkb, Wt, Qb, Kb);
    kRowSum<<<1024, 256, 0, stream>>>(Qb, Kb, lsum);
    kInv<<<16, 256, 0, stream>>>(lsum, linv);
    kColSum<<<1024, 256, 0, stream>>>(Qb, Kb, linv, wsum);
    kY<<<1024, 256, 0, stream>>>(drums, vocals, bass, other, wsum, y, alph);
    kFinal<<<512, 256, 0, stream>>>(DvW, Dvb, VvW, Vvb, y, alph, out);
}

// Round 7
// 345.905 us; speedup vs baseline: 1.0277x; 1.0277x over previous
//
#include <hip/hip_runtime.h>
#include <hip/hip_bf16.h>

typedef __bf16 bf16x8 __attribute__((ext_vector_type(8)));
typedef float  f32x4  __attribute__((ext_vector_type(4)));

#define MFMA(a, b, c) __builtin_amdgcn_mfma_f32_16x16x32_bf16((a), (b), (c), 0, 0, 0)

static constexpr float SC_L2E = 0.03125f * 1.44269504088896341f;  // (1/sqrt(1024)) * log2(e)
static constexpr float INV_NQ = 1.0f / 4096.0f;                   // mean over 4S rows

__device__ inline bf16x8 ld_cvt_bf8(const float* __restrict__ p) {
    f32x4 x0 = *(const f32x4*)p;
    f32x4 x1 = *(const f32x4*)(p + 4);
    bf16x8 r;
    r[0] = (__bf16)x0[0]; r[1] = (__bf16)x0[1]; r[2] = (__bf16)x0[2]; r[3] = (__bf16)x0[3];
    r[4] = (__bf16)x1[0]; r[5] = (__bf16)x1[1]; r[6] = (__bf16)x1[2]; r[7] = (__bf16)x1[3];
    return r;
}

__device__ inline bf16x8 cvt2_bf8(f32x4 a, f32x4 b) {
    bf16x8 r;
    r[0] = (__bf16)a[0]; r[1] = (__bf16)a[1]; r[2] = (__bf16)a[2]; r[3] = (__bf16)a[3];
    r[4] = (__bf16)b[0]; r[5] = (__bf16)b[1]; r[6] = (__bf16)b[2]; r[7] = (__bf16)b[3];
    return r;
}

// ---- Kernel T: transpose 4 projection weights [1024,128] -> bf16 [128,1024] ----
__global__ __launch_bounds__(256) void kT(const float* __restrict__ Dq, const float* __restrict__ Vq,
                                          const float* __restrict__ Dk, const float* __restrict__ Vk,
                                          __bf16* __restrict__ Wt) {
    __shared__ float tile[64][65];
    int bx = blockIdx.x;
    int m = bx >> 5, rt = (bx >> 1) & 15, ct = bx & 1;
    const float* W = (m == 0) ? Dq : (m == 1) ? Vq : (m == 2) ? Dk : Vk;
    int t = threadIdx.x;
    int tr = t >> 6, tc = t & 63;
#pragma unroll
    for (int i = 0; i < 16; i++) {
        int rl = tr + i * 4;
        tile[rl][tc] = W[(size_t)(rt * 64 + rl) * 128 + ct * 64 + tc];
    }
    __syncthreads();
#pragma unroll
    for (int i = 0; i < 16; i++) {
        int cl = tr + i * 4;
        Wt[(size_t)m * 131072 + (size_t)(ct * 64 + cl) * 1024 + rt * 64 + tc] = (__bf16)tile[tc][cl];
    }
}

// ---- Kernel P: pipelined q+k projection partials ----
// grid 1024: [bs(16)=b*4+stem][rowtile(16) of 64 rows][kchunk(4) of 256 k].
// X tile 64x64 staged to LDS (bf16, XOR-swizzled) with register prefetch; 4 waves
// split 256 out-cols (Qlo,Qhi,Klo,Khi); fp32 atomicAdd partials into Qf/Kf.
__global__ __launch_bounds__(256) void kProjP(
    const float* __restrict__ drums, const float* __restrict__ vocals,
    const float* __restrict__ bass,  const float* __restrict__ other,
    const __bf16* __restrict__ Wt, float* __restrict__ Qf, float* __restrict__ Kf) {
    __shared__ char xt[8192];          // 64 rows x 64 bf16 (128 B/row), swizzled
    int bx = blockIdx.x;
    int kc = bx & 3, rt = (bx >> 2) & 15, bs = bx >> 6;
    int b = bs >> 2, stem = bs & 3;
    int rin = rt * 64;
    int k0b = kc * 256;

    const float* X = (stem == 0) ? drums : (stem == 1) ? vocals : (stem == 2) ? bass : other;
    const __bf16* WQ = Wt + (size_t)((stem == 0) ? 0 : 1) * 131072;
    const __bf16* WK = Wt + (size_t)((stem == 0) ? 2 : 3) * 131072;

    int t = threadIdx.x;
    int lane = t & 63, wid = t >> 6;
    int l16 = lane & 15, g = lane >> 4;

    const __bf16* Wm = (wid < 2) ? WQ : WK;
    int colbase = (wid & 1) * 64;
    float* Pf = (wid < 2) ? Qf : Kf;

    // staging: thread -> (row, 64B segment of 16 floats)
    int srow = t >> 2, sseg = t & 3;
    const float* xsrc = X + ((size_t)b * 1024 + rin + srow) * 1024 + k0b + sseg * 16;
    int swz = (srow & 7) << 4;
    char* wrp = xt + srow * 128;

    f32x4 st[4];
#define LOADST(s) { const float* p_ = xsrc + (s) * 64; \
    st[0] = *(const f32x4*)p_; st[1] = *(const f32x4*)(p_ + 4); \
    st[2] = *(const f32x4*)(p_ + 8); st[3] = *(const f32x4*)(p_ + 12); }
    LOADST(0);

    f32x4 acc[4][4];
#pragma unroll
    for (int i = 0; i < 4; i++)
#pragma unroll
        for (int j = 0; j < 4; j++) acc[i][j] = (f32x4){0.f, 0.f, 0.f, 0.f};

    for (int s = 0; s < 4; ++s) {
        if (s) __syncthreads();                 // LDS consumed by previous stage
        bf16x8 c0 = cvt2_bf8(st[0], st[1]);
        bf16x8 c1 = cvt2_bf8(st[2], st[3]);
        *(uint4*)(wrp + ((sseg * 32) ^ swz))      = *(uint4*)&c0;
        *(uint4*)(wrp + ((sseg * 32 + 16) ^ swz)) = *(uint4*)&c1;
        __syncthreads();
        if (s < 3) LOADST(s + 1);
#pragma unroll
        for (int kk = 0; kk < 64; kk += 32) {
            bf16x8 bfr[4];
#pragma unroll
            for (int cf = 0; cf < 4; cf++)
                bfr[cf] = *(const bf16x8*)(Wm + (size_t)(colbase + cf * 16 + l16) * 1024
                                           + k0b + s * 64 + kk + g * 8);
#pragma unroll
            for (int rf = 0; rf < 4; rf++) {
                int row = rf * 16 + l16;
                bf16x8 av = *(const bf16x8*)(xt + row * 128
                                             + (((kk + g * 8) * 2) ^ ((row & 7) << 4)));
#pragma unroll
                for (int cf = 0; cf < 4; cf++)
                    acc[rf][cf] = MFMA(av, bfr[cf], acc[rf][cf]);
            }
        }
    }
#undef LOADST

    size_t grow = (size_t)b * 4096 + (size_t)stem * 1024 + rin;
#pragma unroll
    for (int rf = 0; rf < 4; rf++)
#pragma unroll
        for (int cf = 0; cf < 4; cf++) {
            int col = colbase + cf * 16 + l16;
#pragma unroll
            for (int i = 0; i < 4; i++)
                atomicAdd(&Pf[(grow + rf * 16 + g * 4 + i) * 128 + col], acc[rf][cf][i]);
        }
}

// ---- Kernel B: Qb/Kb = bf16(Qf/Kf + bias). grid 2048 x 256, 8 elems/thread ----
__global__ __launch_bounds__(256) void kBias(
    const float* __restrict__ Qf, const float* __restrict__ Kf,
    const float* __restrict__ Dqb, const float* __restrict__ Vqb,
    const float* __restrict__ Dkb, const float* __restrict__ Vkb,
    __bf16* __restrict__ Qb, __bf16* __restrict__ Kb) {
    int gid = blockIdx.x * 256 + threadIdx.x;   // 524288 total
    int qk  = gid >> 18;
    int rem = gid & 262143;
    int row = rem >> 4, ch = rem & 15;
    int stem = (row >> 10) & 3;
    const float* Pf   = qk ? Kf : Qf;
    const float* bias = qk ? ((stem == 0) ? Dkb : Vkb) : ((stem == 0) ? Dqb : Vqb);
    __bf16* Out = qk ? Kb : Qb;
    int col = ch * 8;
    f32x4 v0 = *(const f32x4*)(Pf + (size_t)row * 128 + col);
    f32x4 v1 = *(const f32x4*)(Pf + (size_t)row * 128 + col + 4);
    f32x4 b0 = *(const f32x4*)(bias + col);
    f32x4 b1 = *(const f32x4*)(bias + col + 4);
    bf16x8 r = cvt2_bf8((f32x4){v0[0]+b0[0], v0[1]+b0[1], v0[2]+b0[2], v0[3]+b0[3]},
                        (f32x4){v1[0]+b1[0], v1[1]+b1[1], v1[2]+b1[2], v1[3]+b1[3]});
    *(bf16x8*)(Out + (size_t)row * 128 + col) = r;
}

// ---- Kernel S1: row sums l[q] = sum_k exp(s_qk) ----
__global__ __launch_bounds__(256) void kRowSum(const __bf16* __restrict__ Qb,
                                               const __bf16* __restrict__ Kb,
                                               float* __restrict__ lsum) {
    __shared__ uint4 ktile[1024];    // 64 rows x 128 bf16 = 16 KB
    int bx = blockIdx.x;
    int cc = bx & 7, tile = (bx >> 3) & 31, b = bx >> 8;
    int lane = threadIdx.x & 63, wid = threadIdx.x >> 6;
    int l16 = lane & 15, g = lane >> 4;
    int R  = tile * 128 + wid * 32;
    int C0 = cc * 512;
    const __bf16* Qr = Qb + (size_t)b * 4096 * 128;
    const __bf16* Kr = Kb + (size_t)b * 4096 * 128;

    bf16x8 a[2][4];
#pragma unroll
    for (int rf = 0; rf < 2; rf++)
#pragma unroll
        for (int kf = 0; kf < 4; kf++)
            a[rf][kf] = *(const bf16x8*)(Qr + (size_t)(R + rf * 16 + l16) * 128 + kf * 32 + g * 8);

    int sr = threadIdx.x >> 2, sseg = threadIdx.x & 3;
    char* kbc = (char*)ktile;
    int swm = (sr & 7) << 4;

    uint4 st[4];
    {
        const char* src = (const char*)(Kr + (size_t)(C0 + sr) * 128) + sseg * 64;
#pragma unroll
        for (int j = 0; j < 4; j++) st[j] = *(const uint4*)(src + j * 16);
    }

    float rs[2][4] = {};
    for (int s = 0; s < 8; ++s) {
        __syncthreads();
#pragma unroll
        for (int j = 0; j < 4; j++)
            *(uint4*)(kbc + sr * 256 + ((sseg * 64 + j * 16) ^ swm)) = st[j];
        __syncthreads();
        if (s < 7) {
            const char* src = (const char*)(Kr + (size_t)(C0 + (s + 1) * 64 + sr) * 128) + sseg * 64;
#pragma unroll
            for (int j = 0; j < 4; j++) st[j] = *(const uint4*)(src + j * 16);
        }
#pragma unroll
        for (int ctl = 0; ctl < 4; ++ctl) {
            int r2 = ctl * 16 + l16;
            int rm = (r2 & 7) << 4;
            f32x4 acc0 = (f32x4){0.f,0.f,0.f,0.f};
            f32x4 acc1 = (f32x4){0.f,0.f,0.f,0.f};
#pragma unroll
            for (int kf = 0; kf < 4; kf++) {
                bf16x8 bv = *(const bf16x8*)(kbc + r2 * 256 + ((kf * 64 + g * 16) ^ rm));
                acc0 = MFMA(a[0][kf], bv, acc0);
                acc1 = MFMA(a[1][kf], bv, acc1);
            }
#pragma unroll
            for (int r = 0; r < 4; r++) {
                rs[0][r] += exp2f(acc0[r] * SC_L2E);
                rs[1][r] += exp2f(acc1[r] * SC_L2E);
            }
        }
    }
#pragma unroll
    for (int rf = 0; rf < 2; rf++)
#pragma unroll
        for (int r = 0; r < 4; r++) {
            float v = rs[rf][r];
#pragma unroll
            for (int m = 1; m < 16; m <<= 1) v += __shfl_xor(v, m);
            if (l16 == 0) atomicAdd(&lsum[(size_t)b * 4096 + R + rf * 16 + g * 4 + r], v);
        }
}

// ---- Kernel I: linv = 1/lsum ----
__global__ __launch_bounds__(256) void kInv(const float* __restrict__ lsum, float* __restrict__ linv) {
    int i = (blockIdx.x * 256 + threadIdx.x) * 4;
    f32x4 v = *(const f32x4*)(lsum + i);
    f32x4 r = (f32x4){1.f / v[0], 1.f / v[1], 1.f / v[2], 1.f / v[3]};
    *(f32x4*)(linv + i) = r;
}

// ---- Kernel S2: col sums w[k] = sum_q exp(s_qk)/l_q ----
__global__ __launch_bounds__(256) void kColSum(const __bf16* __restrict__ Qb,
                                               const __bf16* __restrict__ Kb,
                                               const float* __restrict__ linv,
                                               float* __restrict__ wsum) {
    __shared__ uint4 qtile[1024];
    __shared__ float li[512];
    int bx = blockIdx.x;
    int rc = bx & 7, tile = (bx >> 3) & 31, b = bx >> 8;
    int lane = threadIdx.x & 63, wid = threadIdx.x >> 6;
    int l16 = lane & 15, g = lane >> 4;
    int C  = tile * 128 + wid * 32;
    int R0 = rc * 512;
    const __bf16* Qr = Qb + (size_t)b * 4096 * 128;
    const __bf16* Kr = Kb + (size_t)b * 4096 * 128;

    if (threadIdx.x < 128)
        *(f32x4*)(li + threadIdx.x * 4) = *(const f32x4*)(linv + (size_t)b * 4096 + R0 + threadIdx.x * 4);

    bf16x8 kb[2][4];
#pragma unroll
    for (int cf = 0; cf < 2; cf++)
#pragma unroll
        for (int kf = 0; kf < 4; kf++)
            kb[cf][kf] = *(const bf16x8*)(Kr + (size_t)(C + cf * 16 + l16) * 128 + kf * 32 + g * 8);

    int sr = threadIdx.x >> 2, sseg = threadIdx.x & 3;
    char* qbc = (char*)qtile;
    int swm = (sr & 7) << 4;

    uint4 st[4];
    {
        const char* src = (const char*)(Qr + (size_t)(R0 + sr) * 128) + sseg * 64;
#pragma unroll
        for (int j = 0; j < 4; j++) st[j] = *(const uint4*)(src + j * 16);
    }

    float cs[2] = {0.f, 0.f};
    for (int s = 0; s < 8; ++s) {
        __syncthreads();
#pragma unroll
        for (int j = 0; j < 4; j++)
            *(uint4*)(qbc + sr * 256 + ((sseg * 64 + j * 16) ^ swm)) = st[j];
        __syncthreads();
        if (s < 7) {
            const char* src = (const char*)(Qr + (size_t)(R0 + (s + 1) * 64 + sr) * 128) + sseg * 64;
#pragma unroll
            for (int j = 0; j < 4; j++) st[j] = *(const uint4*)(src + j * 16);
        }
#pragma unroll
        for (int ctl = 0; ctl < 4; ++ctl) {
            int r2 = ctl * 16 + l16;
            int rm = (r2 & 7) << 4;
            f32x4 acc0 = (f32x4){0.f,0.f,0.f,0.f};
            f32x4 acc1 = (f32x4){0.f,0.f,0.f,0.f};
#pragma unroll
            for (int kf = 0; kf < 4; kf++) {
                bf16x8 av = *(const bf16x8*)(qbc + r2 * 256 + ((kf * 64 + g * 16) ^ rm));
                acc0 = MFMA(av, kb[0][kf], acc0);
                acc1 = MFMA(av, kb[1][kf], acc1);
            }
            int ib = s * 64 + ctl * 16 + g * 4;
#pragma unroll
            for (int r = 0; r < 4; r++) {
                float lv = li[ib + r];
                cs[0] += exp2f(acc0[r] * SC_L2E) * lv;
                cs[1] += exp2f(acc1[r] * SC_L2E) * lv;
            }
        }
    }
#pragma unroll
    for (int cf = 0; cf < 2; cf++) {
        float v = cs[cf];
        v += __shfl_xor(v, 16);
        v += __shfl_xor(v, 32);
        if (lane < 16) atomicAdd(&wsum[(size_t)b * 4096 + C + cf * 16 + lane], v);
    }
}

// ---- Kernel Y: weighted stem sums (fp32) ----
__global__ __launch_bounds__(256) void kY(
    const float* __restrict__ drums, const float* __restrict__ vocals,
    const float* __restrict__ bass,  const float* __restrict__ other,
    const float* __restrict__ wsum, float* __restrict__ y, float* __restrict__ alpha) {
    __shared__ float ws[16];
    int bx = blockIdx.x;
    int b = bx >> 8, stem = (bx >> 6) & 3, kc = bx & 63;
    const float* X = (stem == 0) ? drums : (stem == 1) ? vocals : (stem == 2) ? bass : other;
    int t = threadIdx.x;
    float wv = 0.f;
    if (t < 16) { wv = wsum[(size_t)b * 4096 + stem * 1024 + kc * 16 + t] * INV_NQ; ws[t] = wv; }
    __syncthreads();

    f32x4 acc = (f32x4){0.f, 0.f, 0.f, 0.f};
    const float* xp = X + ((size_t)b * 1024 + kc * 16) * 1024 + t * 4;
#pragma unroll 4
    for (int i = 0; i < 16; i++) {
        f32x4 xv = *(const f32x4*)(xp + (size_t)i * 1024);
        float wvi = ws[i];
        acc[0] += wvi * xv[0]; acc[1] += wvi * xv[1]; acc[2] += wvi * xv[2]; acc[3] += wvi * xv[3];
    }
    int seg = (stem == 0) ? 0 : 1;
    float* yp = y + ((size_t)b * 2 + seg) * 1024 + t * 4;
    atomicAdd(yp + 0, acc[0]); atomicAdd(yp + 1, acc[1]);
    atomicAdd(yp + 2, acc[2]); atomicAdd(yp + 3, acc[3]);

    if (t < 16) {
        float s = wv;
        s += __shfl_xor(s, 1); s += __shfl_xor(s, 2);
        s += __shfl_xor(s, 4); s += __shfl_xor(s, 8);
        if (t == 0) atomicAdd(alpha + b * 2 + seg, s);
    }
}

// ---- Kernel F: out[b][d] = yD@DvW + yV@VvW + aD*Dvb + aV*Vvb ----
__global__ __launch_bounds__(256) void kFinal(
    const float* __restrict__ DvW, const float* __restrict__ Dvb,
    const float* __restrict__ VvW, const float* __restrict__ Vvb,
    const float* __restrict__ y, const float* __restrict__ alpha,
    float* __restrict__ out) {
    __shared__ float yD[32], yV[32];
    int bx = blockIdx.x;
    int b = bx >> 7, dstripe = (bx >> 5) & 3, kc = bx & 31;
    int t = threadIdx.x;
    if (t < 32) {
        yD[t] = y[((size_t)b * 2 + 0) * 1024 + kc * 32 + t];
        yV[t] = y[((size_t)b * 2 + 1) * 1024 + kc * 32 + t];
    }
    __syncthreads();

    int d = dstripe * 256 + t;
    const float* pD = DvW + (size_t)(kc * 32) * 1024 + d;
    const float* pV = VvW + (size_t)(kc * 32) * 1024 + d;
    float acc = 0.f;
#pragma unroll 4
    for (int k = 0; k < 32; k++)
        acc += yD[k] * pD[(size_t)k * 1024] + yV[k] * pV[(size_t)k * 1024];
    if (kc == 0) acc += alpha[b * 2] * Dvb[d] + alpha[b * 2 + 1] * Vvb[d];
    atomicAdd(out + (size_t)b * 1024 + d, acc);
}

extern "C" void kernel_launch(void* const* d_in, const int* in_sizes, int n_in,
                              void* d_out, int out_size, void* d_ws, size_t ws_size,
                              hipStream_t stream) {
    const float* drums  = (const float*)d_in[0];
    const float* vocals = (const float*)d_in[1];
    const float* bass   = (const float*)d_in[2];
    const float* other  = (const float*)d_in[3];
    const float* DqW = (const float*)d_in[4];
    const float* Dqb = (const float*)d_in[5];
    const float* DkW = (const float*)d_in[6];
    const float* Dkb = (const float*)d_in[7];
    const float* DvW = (const float*)d_in[8];
    const float* Dvb = (const float*)d_in[9];
    const float* VqW = (const float*)d_in[10];
    const float* Vqb = (const float*)d_in[11];
    const float* VkW = (const float*)d_in[12];
    const float* Vkb = (const float*)d_in[13];
    const float* VvW = (const float*)d_in[14];
    const float* Vvb = (const float*)d_in[15];
    float* out = (float*)d_out;

    char* ws = (char*)d_ws;
    __bf16* Qb   = (__bf16*)(ws);                                  // 4 MB
    __bf16* Kb   = (__bf16*)(ws + (4u << 20));                     // 4 MB
    __bf16* Wt   = (__bf16*)(ws + (8u << 20));                     // 1 MB
    float*  lsum = (float*)(ws + (9u << 20));                      // 64 KB
    float*  wsum = (float*)(ws + (9u << 20) + (64u << 10));        // 64 KB
    float*  y    = (float*)(ws + (9u << 20) + (128u << 10));       // 32 KB
    float*  alph = (float*)(ws + (9u << 20) + (160u << 10));       // 32 B
    float*  linv = (float*)(ws + (9u << 20) + (192u << 10));       // 64 KB
    float*  Qf   = (float*)(ws + (10u << 20));                     // 8 MB
    float*  Kf   = (float*)(ws + (18u << 20));                     // 8 MB

    hipMemsetAsync(lsum, 0, (160u << 10) + 32, stream);
    hipMemsetAsync(Qf, 0, (16u << 20), stream);                    // Qf+Kf contiguous
    hipMemsetAsync(out, 0, (size_t)out_size * sizeof(float), stream);

    kT<<<128, 256, 0, stream>>>(DqW, VqW, DkW, VkW, Wt);
    kProjP<<<1024, 256, 0, stream>>>(drums, vocals, bass, other, Wt, Qf, Kf);
    kBias<<<2048, 256, 0, stream>>>(Qf, Kf, Dqb, Vqb, Dkb, Vkb, Qb, Kb);
    kRowSum<<<1024, 256, 0, stream>>>(Qb, Kb, lsum);
    kInv<<<16, 256, 0, stream>>>(lsum, linv);
    kColSum<<<1024, 256, 0, stream>>>(Qb, Kb, linv, wsum);
    kY<<<1024, 256, 0, stream>>>(drums, vocals, bass, other, wsum, y, alph);
    kFinal<<<512, 256, 0, stream>>>(DvW, Dvb, VvW, Vvb, y, alph, out);
}

// Round 10
// 341.633 us; speedup vs baseline: 1.0406x; 1.0125x over previous
//
#include <hip/hip_runtime.h>
#include <hip/hip_bf16.h>

typedef __bf16 bf16x8 __attribute__((ext_vector_type(8)));
typedef __bf16 bf16x4 __attribute__((ext_vector_type(4)));
typedef float  f32x4  __attribute__((ext_vector_type(4)));

#define MFMA(a, b, c) __builtin_amdgcn_mfma_f32_16x16x32_bf16((a), (b), (c), 0, 0, 0)

static constexpr float SC_L2E = 0.03125f * 1.44269504088896341f;  // (1/sqrt(1024)) * log2(e)
static constexpr float INV_NQ = 1.0f / 4096.0f;                   // mean over 4S rows

// ---- Kernel T: transpose 4 projection weights [1024,128] -> bf16 [128,1024] ----
__global__ __launch_bounds__(256) void kT(const float* __restrict__ Dq, const float* __restrict__ Vq,
                                          const float* __restrict__ Dk, const float* __restrict__ Vk,
                                          __bf16* __restrict__ Wt) {
    __shared__ float tile[64][65];
    int bx = blockIdx.x;
    int m = bx >> 5, rt = (bx >> 1) & 15, ct = bx & 1;
    const float* W = (m == 0) ? Dq : (m == 1) ? Vq : (m == 2) ? Dk : Vk;
    int t = threadIdx.x;
    int tr = t >> 6, tc = t & 63;
#pragma unroll
    for (int i = 0; i < 16; i++) {
        int rl = tr + i * 4;
        tile[rl][tc] = W[(size_t)(rt * 64 + rl) * 128 + ct * 64 + tc];
    }
    __syncthreads();
#pragma unroll
    for (int i = 0; i < 16; i++) {
        int cl = tr + i * 4;
        Wt[(size_t)m * 131072 + (size_t)(ct * 64 + cl) * 1024 + rt * 64 + tc] = (__bf16)tile[tc][cl];
    }
}

// ---- Kernel P2: fused q+k projection, full-K per block, NO atomics ----
// grid 1024: [bs(16)=b*4+stem][rowtile(64) of 16 rows]. 4 waves: (Qlo,Qhi,Klo,Khi),
// each 64 out-cols x 16 rows, K=1024 in 16 LDS stages of 64k (swizzled), weight
// frags register-prefetched 1 kk-step ahead. Direct bf16 store with fused bias.
__global__ __launch_bounds__(256, 4) void kProj2(
    const float* __restrict__ drums, const float* __restrict__ vocals,
    const float* __restrict__ bass,  const float* __restrict__ other,
    const float* __restrict__ Dqb, const float* __restrict__ Vqb,
    const float* __restrict__ Dkb, const float* __restrict__ Vkb,
    const __bf16* __restrict__ Wt, __bf16* __restrict__ Qb, __bf16* __restrict__ Kb) {
    __shared__ uint4 xt4[128];         // 16 rows x 64 bf16 (128 B/row), swizzled
    char* xt = (char*)xt4;
    int bx = blockIdx.x;
    int rt = bx & 63, bs = bx >> 6;
    int b = bs >> 2, stem = bs & 3;
    int rin = rt * 16;

    const float* X = (stem == 0) ? drums : (stem == 1) ? vocals : (stem == 2) ? bass : other;
    const __bf16* WQ = Wt + (size_t)((stem == 0) ? 0 : 1) * 131072;
    const __bf16* WK = Wt + (size_t)((stem == 0) ? 2 : 3) * 131072;

    int t = threadIdx.x, lane = t & 63, wid = t >> 6;
    int l16 = lane & 15, g = lane >> 4;

    const __bf16* Wm   = (wid < 2) ? WQ : WK;
    const float*  bias = (wid < 2) ? ((stem == 0) ? Dqb : Vqb) : ((stem == 0) ? Dkb : Vkb);
    __bf16*       Out  = (wid < 2) ? Qb : Kb;
    int colbase = (wid & 1) * 64;

    // staging: thread -> (row srow, 4-float segment sc4)
    int srow = t >> 4, sc4 = t & 15;
    const float* xsrc = X + ((size_t)b * 1024 + rin + srow) * 1024 + sc4 * 4;
    int swz = (srow & 7) << 4;
    char* wrp = xt + srow * 128;
    int wb = sc4 * 8;

    const __bf16* wp = Wm + (size_t)(colbase + l16) * 1024;  // + cf*16*1024 + k + g*8

    f32x4 stg = *(const f32x4*)xsrc;
    bf16x8 bcur[4], bnxt[4];
#pragma unroll
    for (int cf = 0; cf < 4; cf++) bcur[cf] = *(const bf16x8*)(wp + cf * 16384 + g * 8);

    f32x4 acc[4];
#pragma unroll
    for (int cf = 0; cf < 4; cf++) acc[cf] = (f32x4){0.f, 0.f, 0.f, 0.f};

    for (int s = 0; s < 16; ++s) {
        if (s) __syncthreads();
        bf16x4 c;
        c[0] = (__bf16)stg[0]; c[1] = (__bf16)stg[1];
        c[2] = (__bf16)stg[2]; c[3] = (__bf16)stg[3];
        *(bf16x4*)(wrp + (wb ^ swz)) = c;
        __syncthreads();
        if (s < 15) stg = *(const f32x4*)(xsrc + (s + 1) * 64);
#pragma unroll
        for (int kk = 0; kk < 2; ++kk) {
            if (kk == 0 || s < 15) {
                int knk = (kk == 0) ? s * 64 + 32 : (s + 1) * 64;
#pragma unroll
                for (int cf = 0; cf < 4; cf++)
                    bnxt[cf] = *(const bf16x8*)(wp + cf * 16384 + knk + g * 8);
            }
            bf16x8 av = *(const bf16x8*)(xt + l16 * 128 + ((kk * 64 + g * 16) ^ ((l16 & 7) << 4)));
#pragma unroll
            for (int cf = 0; cf < 4; cf++) acc[cf] = MFMA(av, bcur[cf], acc[cf]);
#pragma unroll
            for (int cf = 0; cf < 4; cf++) bcur[cf] = bnxt[cf];
        }
    }

    size_t grow = (size_t)b * 4096 + (size_t)stem * 1024 + rin;
#pragma unroll
    for (int cf = 0; cf < 4; cf++) {
        int col = colbase + cf * 16 + l16;
        float bv = bias[col];
#pragma unroll
        for (int i = 0; i < 4; i++)
            Out[(grow + g * 4 + i) * 128 + col] = (__bf16)(acc[cf][i] + bv);
    }
}

// ---- Kernel S1: row sums l[q] = sum_k exp(s_qk) ----
// grid 2048: [b(4)][rowtile(32)][colchunk(16)]; wave 32 rows x 256-col stream.
__global__ __launch_bounds__(256) void kRowSum(const __bf16* __restrict__ Qb,
                                               const __bf16* __restrict__ Kb,
                                               float* __restrict__ lsum) {
    __shared__ uint4 ktile[1024];    // 64 rows x 128 bf16 = 16 KB
    int bx = blockIdx.x;
    int cc = bx & 15, tile = (bx >> 4) & 31, b = bx >> 9;
    int lane = threadIdx.x & 63, wid = threadIdx.x >> 6;
    int l16 = lane & 15, g = lane >> 4;
    int R  = tile * 128 + wid * 32;
    int C0 = cc * 256;
    const __bf16* Qr = Qb + (size_t)b * 4096 * 128;
    const __bf16* Kr = Kb + (size_t)b * 4096 * 128;

    bf16x8 a[2][4];
#pragma unroll
    for (int rf = 0; rf < 2; rf++)
#pragma unroll
        for (int kf = 0; kf < 4; kf++)
            a[rf][kf] = *(const bf16x8*)(Qr + (size_t)(R + rf * 16 + l16) * 128 + kf * 32 + g * 8);

    int sr = threadIdx.x >> 2, sseg = threadIdx.x & 3;
    char* kbc = (char*)ktile;
    int swm = (sr & 7) << 4;

    uint4 st[4];
    {
        const char* src = (const char*)(Kr + (size_t)(C0 + sr) * 128) + sseg * 64;
#pragma unroll
        for (int j = 0; j < 4; j++) st[j] = *(const uint4*)(src + j * 16);
    }

    float rs[2][4] = {};
    for (int s = 0; s < 4; ++s) {
        __syncthreads();
#pragma unroll
        for (int j = 0; j < 4; j++)
            *(uint4*)(kbc + sr * 256 + ((sseg * 64 + j * 16) ^ swm)) = st[j];
        __syncthreads();
        if (s < 3) {
            const char* src = (const char*)(Kr + (size_t)(C0 + (s + 1) * 64 + sr) * 128) + sseg * 64;
#pragma unroll
            for (int j = 0; j < 4; j++) st[j] = *(const uint4*)(src + j * 16);
        }
#pragma unroll
        for (int ctl = 0; ctl < 4; ++ctl) {
            int r2 = ctl * 16 + l16;
            int rm = (r2 & 7) << 4;
            f32x4 acc0 = (f32x4){0.f,0.f,0.f,0.f};
            f32x4 acc1 = (f32x4){0.f,0.f,0.f,0.f};
#pragma unroll
            for (int kf = 0; kf < 4; kf++) {
                bf16x8 bv = *(const bf16x8*)(kbc + r2 * 256 + ((kf * 64 + g * 16) ^ rm));
                acc0 = MFMA(a[0][kf], bv, acc0);
                acc1 = MFMA(a[1][kf], bv, acc1);
            }
#pragma unroll
            for (int r = 0; r < 4; r++) {
                rs[0][r] += exp2f(acc0[r] * SC_L2E);
                rs[1][r] += exp2f(acc1[r] * SC_L2E);
            }
        }
    }
#pragma unroll
    for (int rf = 0; rf < 2; rf++)
#pragma unroll
        for (int r = 0; r < 4; r++) {
            float v = rs[rf][r];
#pragma unroll
            for (int m = 1; m < 16; m <<= 1) v += __shfl_xor(v, m);
            if (l16 == 0) atomicAdd(&lsum[(size_t)b * 4096 + R + rf * 16 + g * 4 + r], v);
        }
}

// ---- Kernel I: linv = 1/lsum ----
__global__ __launch_bounds__(256) void kInv(const float* __restrict__ lsum, float* __restrict__ linv) {
    int i = (blockIdx.x * 256 + threadIdx.x) * 4;
    f32x4 v = *(const f32x4*)(lsum + i);
    f32x4 r = (f32x4){1.f / v[0], 1.f / v[1], 1.f / v[2], 1.f / v[3]};
    *(f32x4*)(linv + i) = r;
}

// ---- Kernel S2: col sums w[k] = sum_q exp(s_qk)/l_q ----
// grid 2048: [b(4)][coltile(32)][rowchunk(16)]; wave 32 cols x 256-row stream.
__global__ __launch_bounds__(256) void kColSum(const __bf16* __restrict__ Qb,
                                               const __bf16* __restrict__ Kb,
                                               const float* __restrict__ linv,
                                               float* __restrict__ wsum) {
    __shared__ uint4 qtile[1024];
    __shared__ float li[256];
    int bx = blockIdx.x;
    int rc = bx & 15, tile = (bx >> 4) & 31, b = bx >> 9;
    int lane = threadIdx.x & 63, wid = threadIdx.x >> 6;
    int l16 = lane & 15, g = lane >> 4;
    int C  = tile * 128 + wid * 32;
    int R0 = rc * 256;
    const __bf16* Qr = Qb + (size_t)b * 4096 * 128;
    const __bf16* Kr = Kb + (size_t)b * 4096 * 128;

    if (threadIdx.x < 64)
        *(f32x4*)(li + threadIdx.x * 4) = *(const f32x4*)(linv + (size_t)b * 4096 + R0 + threadIdx.x * 4);

    bf16x8 kb[2][4];
#pragma unroll
    for (int cf = 0; cf < 2; cf++)
#pragma unroll
        for (int kf = 0; kf < 4; kf++)
            kb[cf][kf] = *(const bf16x8*)(Kr + (size_t)(C + cf * 16 + l16) * 128 + kf * 32 + g * 8);

    int sr = threadIdx.x >> 2, sseg = threadIdx.x & 3;
    char* qbc = (char*)qtile;
    int swm = (sr & 7) << 4;

    uint4 st[4];
    {
        const char* src = (const char*)(Qr + (size_t)(R0 + sr) * 128) + sseg * 64;
#pragma unroll
        for (int j = 0; j < 4; j++) st[j] = *(const uint4*)(src + j * 16);
    }

    float cs[2] = {0.f, 0.f};
    for (int s = 0; s < 4; ++s) {
        __syncthreads();
#pragma unroll
        for (int j = 0; j < 4; j++)
            *(uint4*)(qbc + sr * 256 + ((sseg * 64 + j * 16) ^ swm)) = st[j];
        __syncthreads();
        if (s < 3) {
            const char* src = (const char*)(Qr + (size_t)(R0 + (s + 1) * 64 + sr) * 128) + sseg * 64;
#pragma unroll
            for (int j = 0; j < 4; j++) st[j] = *(const uint4*)(src + j * 16);
        }
#pragma unroll
        for (int ctl = 0; ctl < 4; ++ctl) {
            int r2 = ctl * 16 + l16;
            int rm = (r2 & 7) << 4;
            f32x4 acc0 = (f32x4){0.f,0.f,0.f,0.f};
            f32x4 acc1 = (f32x4){0.f,0.f,0.f,0.f};
#pragma unroll
            for (int kf = 0; kf < 4; kf++) {
                bf16x8 av = *(const bf16x8*)(qbc + r2 * 256 + ((kf * 64 + g * 16) ^ rm));
                acc0 = MFMA(av, kb[0][kf], acc0);
                acc1 = MFMA(av, kb[1][kf], acc1);
            }
            int ib = s * 64 + ctl * 16 + g * 4;
#pragma unroll
            for (int r = 0; r < 4; r++) {
                float lv = li[ib + r];
                cs[0] += exp2f(acc0[r] * SC_L2E) * lv;
                cs[1] += exp2f(acc1[r] * SC_L2E) * lv;
            }
        }
    }
#pragma unroll
    for (int cf = 0; cf < 2; cf++) {
        float v = cs[cf];
        v += __shfl_xor(v, 16);
        v += __shfl_xor(v, 32);
        if (lane < 16) atomicAdd(&wsum[(size_t)b * 4096 + C + cf * 16 + lane], v);
    }
}

// ---- Kernel Y: weighted stem sums (fp32) ----
__global__ __launch_bounds__(256) void kY(
    const float* __restrict__ drums, const float* __restrict__ vocals,
    const float* __restrict__ bass,  const float* __restrict__ other,
    const float* __restrict__ wsum, float* __restrict__ y, float* __restrict__ alpha) {
    __shared__ float ws[16];
    int bx = blockIdx.x;
    int b = bx >> 8, stem = (bx >> 6) & 3, kc = bx & 63;
    const float* X = (stem == 0) ? drums : (stem == 1) ? vocals : (stem == 2) ? bass : other;
    int t = threadIdx.x;
    float wv = 0.f;
    if (t < 16) { wv = wsum[(size_t)b * 4096 + stem * 1024 + kc * 16 + t] * INV_NQ; ws[t] = wv; }
    __syncthreads();

    f32x4 acc = (f32x4){0.f, 0.f, 0.f, 0.f};
    const float* xp = X + ((size_t)b * 1024 + kc * 16) * 1024 + t * 4;
#pragma unroll 4
    for (int i = 0; i < 16; i++) {
        f32x4 xv = *(const f32x4*)(xp + (size_t)i * 1024);
        float wvi = ws[i];
        acc[0] += wvi * xv[0]; acc[1] += wvi * xv[1]; acc[2] += wvi * xv[2]; acc[3] += wvi * xv[3];
    }
    int seg = (stem == 0) ? 0 : 1;
    float* yp = y + ((size_t)b * 2 + seg) * 1024 + t * 4;
    atomicAdd(yp + 0, acc[0]); atomicAdd(yp + 1, acc[1]);
    atomicAdd(yp + 2, acc[2]); atomicAdd(yp + 3, acc[3]);

    if (t < 16) {
        float s = wv;
        s += __shfl_xor(s, 1); s += __shfl_xor(s, 2);
        s += __shfl_xor(s, 4); s += __shfl_xor(s, 8);
        if (t == 0) atomicAdd(alpha + b * 2 + seg, s);
    }
}

// ---- Kernel F: out[b][d] = yD@DvW + yV@VvW + aD*Dvb + aV*Vvb ----
__global__ __launch_bounds__(256) void kFinal(
    const float* __restrict__ DvW, const float* __restrict__ Dvb,
    const float* __restrict__ VvW, const float* __restrict__ Vvb,
    const float* __restrict__ y, const float* __restrict__ alpha,
    float* __restrict__ out) {
    __shared__ float yD[32], yV[32];
    int bx = blockIdx.x;
    int b = bx >> 7, dstripe = (bx >> 5) & 3, kc = bx & 31;
    int t = threadIdx.x;
    if (t < 32) {
        yD[t] = y[((size_t)b * 2 + 0) * 1024 + kc * 32 + t];
        yV[t] = y[((size_t)b * 2 + 1) * 1024 + kc * 32 + t];
    }
    __syncthreads();

    int d = dstripe * 256 + t;
    const float* pD = DvW + (size_t)(kc * 32) * 1024 + d;
    const float* pV = VvW + (size_t)(kc * 32) * 1024 + d;
    float acc = 0.f;
#pragma unroll 4
    for (int k = 0; k < 32; k++)
        acc += yD[k] * pD[(size_t)k * 1024] + yV[k] * pV[(size_t)k * 1024];
    if (kc == 0) acc += alpha[b * 2] * Dvb[d] + alpha[b * 2 + 1] * Vvb[d];
    atomicAdd(out + (size_t)b * 1024 + d, acc);
}

extern "C" void kernel_launch(void* const* d_in, const int* in_sizes, int n_in,
                              void* d_out, int out_size, void* d_ws, size_t ws_size,
                              hipStream_t stream) {
    const float* drums  = (const float*)d_in[0];
    const float* vocals = (const float*)d_in[1];
    const float* bass   = (const float*)d_in[2];
    const float* other  = (const float*)d_in[3];
    const float* DqW = (const float*)d_in[4];
    const float* Dqb = (const float*)d_in[5];
    const float* DkW = (const float*)d_in[6];
    const float* Dkb = (const float*)d_in[7];
    const float* DvW = (const float*)d_in[8];
    const float* Dvb = (const float*)d_in[9];
    const float* VqW = (const float*)d_in[10];
    const float* Vqb = (const float*)d_in[11];
    const float* VkW = (const float*)d_in[12];
    const float* Vkb = (const float*)d_in[13];
    const float* VvW = (const float*)d_in[14];
    const float* Vvb = (const float*)d_in[15];
    float* out = (float*)d_out;

    char* ws = (char*)d_ws;
    __bf16* Qb   = (__bf16*)(ws);                                  // 4 MB
    __bf16* Kb   = (__bf16*)(ws + (4u << 20));                     // 4 MB
    __bf16* Wt   = (__bf16*)(ws + (8u << 20));                     // 1 MB
    float*  lsum = (float*)(ws + (9u << 20));                      // 64 KB
    float*  wsum = (float*)(ws + (9u << 20) + (64u << 10));        // 64 KB
    float*  y    = (float*)(ws + (9u << 20) + (128u << 10));       // 32 KB
    float*  alph = (float*)(ws + (9u << 20) + (160u << 10));       // 32 B
    float*  linv = (float*)(ws + (9u << 20) + (192u << 10));       // 64 KB

    hipMemsetAsync(lsum, 0, (160u << 10) + 32, stream);
    hipMemsetAsync(out, 0, (size_t)out_size * sizeof(float), stream);

    kT<<<128, 256, 0, stream>>>(DqW, VqW, DkW, VkW, Wt);
    kProj2<<<1024, 256, 0, stream>>>(drums, vocals, bass, other, Dqb, Vqb, Dkb, Vkb, Wt, Qb, Kb);
    kRowSum<<<2048, 256, 0, stream>>>(Qb, Kb, lsum);
    kInv<<<16, 256, 0, stream>>>(lsum, linv);
    kColSum<<<2048, 256, 0, stream>>>(Qb, Kb, linv, wsum);
    kY<<<1024, 256, 0, stream>>>(drums, vocals, bass, other, wsum, y, alph);
    kFinal<<<512, 256, 0, stream>>>(DvW, Dvb, VvW, Vvb, y, alph, out);
}